// Round 1
// baseline (2852.443 us; speedup 1.0000x reference)
//
#include <hip/hip_runtime.h>

#define DF 128
#define BN_EPS 1e-5f

// XOR swizzle for k-major LDS tiles: spreads the 4-row/4-col groups across banks.
__device__ __forceinline__ int sw4(int kk) { return ((kk >> 2) & 7) << 2; }

// ---------------------------------------------------------------------------
// Dual GEMM: support = x @ W^T + b  (ws), res = x @ Wres^T + bres (d_out)
// Tile: 128 rows x 64 cols per block, 256 threads, thread tile 8x4, K chunked 64.
// ---------------------------------------------------------------------------
__global__ __launch_bounds__(256) void gemm_dual(
    const float* __restrict__ x,
    const float* __restrict__ W, const float* __restrict__ b,
    const float* __restrict__ Wres, const float* __restrict__ bres,
    float* __restrict__ support, float* __restrict__ res, int N)
{
    __shared__ float xs[64][132];   // [k][row^swz], padded: 16B-aligned rows, low conflict
    __shared__ float wt[64][68];    // [k][col^swz]

    const int tid = threadIdx.x;
    const int tx  = tid & 15;       // -> cols tx*4 .. +3
    const int ty  = tid >> 4;       // -> rows ty*8 .. +7
    const int r0  = blockIdx.x * 128;
    const int colbase = blockIdx.y * 64;          // 0,64 -> W ; 128,192 -> Wres
    const float* Wsrc = (colbase < DF) ? W    : Wres;
    const float* bsrc = (colbase < DF) ? b    : bres;
    float*       osrc = (colbase < DF) ? support : res;
    const int coff = colbase & (DF - 1);

    float acc[8][4];
#pragma unroll
    for (int r = 0; r < 8; ++r)
#pragma unroll
        for (int c = 0; c < 4; ++c) acc[r][c] = 0.f;

    for (int kc = 0; kc < 2; ++kc) {
        __syncthreads();
        // stage x tile: 64 k x 128 rows (transposed to k-major)
#pragma unroll
        for (int i = 0; i < 8; ++i) {
            int idx = tid + i * 256;          // 0..2047
            int row = idx >> 4;               // 0..127
            int f4  = idx & 15;               // 0..15 (k-float4 within chunk)
            float4 v = make_float4(0.f, 0.f, 0.f, 0.f);
            int grow = r0 + row;
            if (grow < N)
                v = reinterpret_cast<const float4*>(x)[(size_t)grow * 32 + kc * 16 + f4];
            int rs = row ^ ((f4 & 7) << 2);   // sw4(kk) with kk = f4*4+jj
            xs[f4 * 4 + 0][rs] = v.x;
            xs[f4 * 4 + 1][rs] = v.y;
            xs[f4 * 4 + 2][rs] = v.z;
            xs[f4 * 4 + 3][rs] = v.w;
        }
        // stage W tile: 64 k x 64 cols
#pragma unroll
        for (int i = 0; i < 4; ++i) {
            int idx = tid + i * 256;          // 0..1023
            int col = idx >> 4;               // 0..63
            int f4  = idx & 15;
            float4 v = reinterpret_cast<const float4*>(Wsrc)[(size_t)(coff + col) * 32 + kc * 16 + f4];
            int cs = col ^ ((f4 & 7) << 2);
            wt[f4 * 4 + 0][cs] = v.x;
            wt[f4 * 4 + 1][cs] = v.y;
            wt[f4 * 4 + 2][cs] = v.z;
            wt[f4 * 4 + 3][cs] = v.w;
        }
        __syncthreads();
#pragma unroll 4
        for (int kk = 0; kk < 64; ++kk) {
            const int s = sw4(kk);
            const float4 a0 = *reinterpret_cast<const float4*>(&xs[kk][(ty * 8) ^ s]);
            const float4 a1 = *reinterpret_cast<const float4*>(&xs[kk][(ty * 8 + 4) ^ s]);
            const float4 bb = *reinterpret_cast<const float4*>(&wt[kk][(tx * 4) ^ s]);
            const float a[8]  = {a0.x, a0.y, a0.z, a0.w, a1.x, a1.y, a1.z, a1.w};
            const float bv[4] = {bb.x, bb.y, bb.z, bb.w};
#pragma unroll
            for (int r = 0; r < 8; ++r)
#pragma unroll
                for (int c = 0; c < 4; ++c)
                    acc[r][c] = fmaf(a[r], bv[c], acc[r][c]);
        }
    }

    const float4 bias = reinterpret_cast<const float4*>(bsrc)[(coff >> 2) + tx];
#pragma unroll
    for (int r = 0; r < 8; ++r) {
        int grow = r0 + ty * 8 + r;
        if (grow < N) {
            float4 o = make_float4(acc[r][0] + bias.x, acc[r][1] + bias.y,
                                   acc[r][2] + bias.z, acc[r][3] + bias.w);
            reinterpret_cast<float4*>(osrc)[(size_t)grow * 32 + (coff >> 2) + tx] = o;
        }
    }
}

// ---------------------------------------------------------------------------
// SpMM scatter: agg[dst] += w_e * support[src].  32 lanes per edge, float4 each.
// ---------------------------------------------------------------------------
__global__ __launch_bounds__(256) void spmm_atomic(
    const float* __restrict__ support, const int* __restrict__ src,
    const int* __restrict__ dst, const float* __restrict__ ew,
    float* __restrict__ agg, long total)
{
    long t = (long)blockIdx.x * 256 + threadIdx.x;
    if (t >= total) return;
    int e = (int)(t >> 5);
    int c = (int)(t & 31);
    int s = src[e];
    int d = dst[e];
    float w = ew[e];
    float4 v = reinterpret_cast<const float4*>(support)[(size_t)s * 32 + c];
    float* o = agg + (size_t)d * 128 + c * 4;
    unsafeAtomicAdd(o + 0, v.x * w);
    unsafeAtomicAdd(o + 1, v.y * w);
    unsafeAtomicAdd(o + 2, v.z * w);
    unsafeAtomicAdd(o + 3, v.w * w);
}

// ---------------------------------------------------------------------------
// Column stats: bnacc[0:128] = sum, bnacc[128:256] = sumsq  (over N rows)
// ---------------------------------------------------------------------------
__global__ __launch_bounds__(256) void bn_stats(
    const float* __restrict__ agg, float* __restrict__ bnacc, int N)
{
    const int j    = threadIdx.x & 127;
    const int half = threadIdx.x >> 7;
    const int strm = blockIdx.x * 2 + half;
    const int S    = gridDim.x * 2;
    float s = 0.f, s2 = 0.f;
    for (int r = strm; r < N; r += S) {
        float v = agg[(size_t)r * 128 + j];
        s += v;
        s2 += v * v;
    }
    __shared__ float sh[512];
    sh[threadIdx.x]       = s;
    sh[256 + threadIdx.x] = s2;
    __syncthreads();
    if (threadIdx.x < 128) {
        float ts = sh[threadIdx.x] + sh[threadIdx.x + 128];
        float t2 = sh[256 + threadIdx.x] + sh[256 + threadIdx.x + 128];
        unsafeAtomicAdd(&bnacc[j], ts);
        unsafeAtomicAdd(&bnacc[128 + j], t2);
    }
}

__global__ void bn_finalize(const float* __restrict__ bnacc,
                            const float* __restrict__ gamma,
                            const float* __restrict__ beta,
                            float* __restrict__ scsh, float invN)
{
    int j = threadIdx.x;                 // 128 threads
    float mean = bnacc[j] * invN;
    float var  = bnacc[128 + j] * invN - mean * mean;
    float sc   = gamma[j] * rsqrtf(var + BN_EPS);
    scsh[j]       = sc;
    scsh[128 + j] = beta[j] - mean * sc;
}

// ---------------------------------------------------------------------------
// out = relu(agg*scale + shift) + res   (res already in d_out)
// ---------------------------------------------------------------------------
__global__ __launch_bounds__(256) void bn_apply(
    const float* __restrict__ agg, const float* __restrict__ scsh,
    float* __restrict__ out, long total4)
{
    long t = (long)blockIdx.x * 256 + threadIdx.x;
    if (t >= total4) return;
    int f4 = (int)(t & 31);
    float4 v  = reinterpret_cast<const float4*>(agg)[t];
    float4 sc = reinterpret_cast<const float4*>(scsh)[f4];
    float4 sh = reinterpret_cast<const float4*>(scsh)[32 + f4];
    float4 r  = reinterpret_cast<float4*>(out)[t];
    float4 o;
    o.x = fmaxf(fmaf(v.x, sc.x, sh.x), 0.f) + r.x;
    o.y = fmaxf(fmaf(v.y, sc.y, sh.y), 0.f) + r.y;
    o.z = fmaxf(fmaf(v.z, sc.z, sh.z), 0.f) + r.z;
    o.w = fmaxf(fmaf(v.w, sc.w, sh.w), 0.f) + r.w;
    reinterpret_cast<float4*>(out)[t] = o;
}

// ---------------------------------------------------------------------------
extern "C" void kernel_launch(void* const* d_in, const int* in_sizes, int n_in,
                              void* d_out, int out_size, void* d_ws, size_t ws_size,
                              hipStream_t stream)
{
    const float* x     = (const float*)d_in[0];
    const int*   ei    = (const int*)  d_in[1];
    const float* ew    = (const float*)d_in[2];
    const float* W     = (const float*)d_in[3];
    const float* b     = (const float*)d_in[4];
    const float* Wres  = (const float*)d_in[5];
    const float* bres  = (const float*)d_in[6];
    const float* gamma = (const float*)d_in[7];
    const float* beta  = (const float*)d_in[8];

    const int N = in_sizes[0] / DF;
    const int E = in_sizes[2];
    const int* srci = ei;          // edge_index[0]
    const int* dsti = ei + E;      // edge_index[1]

    // ws layout (floats): agg[N*128] | bnacc[256] | scsh[256] | support[N*128]
    float* fws     = (float*)d_ws;
    float* agg     = fws;
    float* bnacc   = agg + (size_t)N * DF;
    float* scsh    = bnacc + 256;
    float* support = scsh + 256;
    float* out     = (float*)d_out;

    // zero agg + bn accumulators in one shot
    hipMemsetAsync(agg, 0, ((size_t)N * DF + 256) * sizeof(float), stream);

    dim3 gg((N + 127) / 128, 4);
    gemm_dual<<<gg, 256, 0, stream>>>(x, W, b, Wres, bres, support, out, N);

    long total = (long)E * 32;
    int nb = (int)((total + 255) / 256);
    spmm_atomic<<<nb, 256, 0, stream>>>(support, srci, dsti, ew, agg, total);

    bn_stats<<<512, 256, 0, stream>>>(agg, bnacc, N);
    bn_finalize<<<1, 128, 0, stream>>>(bnacc, gamma, beta, scsh, 1.0f / (float)N);

    long t4 = (long)N * (DF / 4);
    bn_apply<<<(int)((t4 + 255) / 256), 256, 0, stream>>>(agg, scsh, out, t4);
}

// Round 2
// 499.476 us; speedup vs baseline: 5.7109x; 5.7109x over previous
//
#include <hip/hip_runtime.h>

#define DF 128
#define BN_EPS 1e-5f

// XOR swizzle for k-major LDS tiles: spreads the 4-row/4-col groups across banks.
__device__ __forceinline__ int sw4(int kk) { return ((kk >> 2) & 7) << 2; }

// ---------------------------------------------------------------------------
// Dual GEMM: support = x @ W^T + b  (ws), res = x @ Wres^T + bres (d_out)
// Tile: 128 rows x 64 cols per block, 256 threads, thread tile 8x4, K chunked 64.
// ---------------------------------------------------------------------------
__global__ __launch_bounds__(256) void gemm_dual(
    const float* __restrict__ x,
    const float* __restrict__ W, const float* __restrict__ b,
    const float* __restrict__ Wres, const float* __restrict__ bres,
    float* __restrict__ support, float* __restrict__ res, int N)
{
    __shared__ float xs[64][132];
    __shared__ float wt[64][68];

    const int tid = threadIdx.x;
    const int tx  = tid & 15;
    const int ty  = tid >> 4;
    const int r0  = blockIdx.x * 128;
    const int colbase = blockIdx.y * 64;          // 0,64 -> W ; 128,192 -> Wres
    const float* Wsrc = (colbase < DF) ? W    : Wres;
    const float* bsrc = (colbase < DF) ? b    : bres;
    float*       osrc = (colbase < DF) ? support : res;
    const int coff = colbase & (DF - 1);

    float acc[8][4];
#pragma unroll
    for (int r = 0; r < 8; ++r)
#pragma unroll
        for (int c = 0; c < 4; ++c) acc[r][c] = 0.f;

    for (int kc = 0; kc < 2; ++kc) {
        __syncthreads();
#pragma unroll
        for (int i = 0; i < 8; ++i) {
            int idx = tid + i * 256;
            int row = idx >> 4;
            int f4  = idx & 15;
            float4 v = make_float4(0.f, 0.f, 0.f, 0.f);
            int grow = r0 + row;
            if (grow < N)
                v = reinterpret_cast<const float4*>(x)[(size_t)grow * 32 + kc * 16 + f4];
            int rs = row ^ ((f4 & 7) << 2);
            xs[f4 * 4 + 0][rs] = v.x;
            xs[f4 * 4 + 1][rs] = v.y;
            xs[f4 * 4 + 2][rs] = v.z;
            xs[f4 * 4 + 3][rs] = v.w;
        }
#pragma unroll
        for (int i = 0; i < 4; ++i) {
            int idx = tid + i * 256;
            int col = idx >> 4;
            int f4  = idx & 15;
            float4 v = reinterpret_cast<const float4*>(Wsrc)[(size_t)(coff + col) * 32 + kc * 16 + f4];
            int cs = col ^ ((f4 & 7) << 2);
            wt[f4 * 4 + 0][cs] = v.x;
            wt[f4 * 4 + 1][cs] = v.y;
            wt[f4 * 4 + 2][cs] = v.z;
            wt[f4 * 4 + 3][cs] = v.w;
        }
        __syncthreads();
#pragma unroll 4
        for (int kk = 0; kk < 64; ++kk) {
            const int s = sw4(kk);
            const float4 a0 = *reinterpret_cast<const float4*>(&xs[kk][(ty * 8) ^ s]);
            const float4 a1 = *reinterpret_cast<const float4*>(&xs[kk][(ty * 8 + 4) ^ s]);
            const float4 bb = *reinterpret_cast<const float4*>(&wt[kk][(tx * 4) ^ s]);
            const float a[8]  = {a0.x, a0.y, a0.z, a0.w, a1.x, a1.y, a1.z, a1.w};
            const float bv[4] = {bb.x, bb.y, bb.z, bb.w};
#pragma unroll
            for (int r = 0; r < 8; ++r)
#pragma unroll
                for (int c = 0; c < 4; ++c)
                    acc[r][c] = fmaf(a[r], bv[c], acc[r][c]);
        }
    }

    const float4 bias = reinterpret_cast<const float4*>(bsrc)[(coff >> 2) + tx];
#pragma unroll
    for (int r = 0; r < 8; ++r) {
        int grow = r0 + ty * 8 + r;
        if (grow < N) {
            float4 o = make_float4(acc[r][0] + bias.x, acc[r][1] + bias.y,
                                   acc[r][2] + bias.z, acc[r][3] + bias.w);
            reinterpret_cast<float4*>(osrc)[(size_t)grow * 32 + (coff >> 2) + tx] = o;
        }
    }
}

// ---------------------------------------------------------------------------
// CSR build
// ---------------------------------------------------------------------------
__global__ __launch_bounds__(256) void hist_deg(
    const int* __restrict__ dst, int* __restrict__ deg, int E)
{
    int i = blockIdx.x * 256 + threadIdx.x;
    if (i < E) atomicAdd(&deg[dst[i]], 1);
}

// per-block inclusive scan -> exclusive local offsets + block partial sums
__global__ __launch_bounds__(256) void scan1(
    const int* __restrict__ deg, int* __restrict__ rowptr,
    int* __restrict__ partial, int N)
{
    __shared__ int sh[256];
    int i = blockIdx.x * 256 + threadIdx.x;
    int v = (i < N) ? deg[i] : 0;
    sh[threadIdx.x] = v;
    __syncthreads();
#pragma unroll
    for (int off = 1; off < 256; off <<= 1) {
        int t = (threadIdx.x >= off) ? sh[threadIdx.x - off] : 0;
        __syncthreads();
        sh[threadIdx.x] += t;
        __syncthreads();
    }
    if (i < N) rowptr[i] = sh[threadIdx.x] - v;          // exclusive
    if (threadIdx.x == 255) partial[blockIdx.x] = sh[255];
}

__global__ __launch_bounds__(256) void scan2(int* __restrict__ partial, int NB)
{
    __shared__ int sh[256];
    int v = (threadIdx.x < NB) ? partial[threadIdx.x] : 0;
    sh[threadIdx.x] = v;
    __syncthreads();
#pragma unroll
    for (int off = 1; off < 256; off <<= 1) {
        int t = (threadIdx.x >= off) ? sh[threadIdx.x - off] : 0;
        __syncthreads();
        sh[threadIdx.x] += t;
        __syncthreads();
    }
    if (threadIdx.x < NB) partial[threadIdx.x] = sh[threadIdx.x] - v;  // exclusive
}

__global__ __launch_bounds__(256) void scan3(
    int* __restrict__ rowptr, int* __restrict__ cursor,
    const int* __restrict__ partial, int N)
{
    int i = blockIdx.x * 256 + threadIdx.x;
    if (i < N) {
        int r = rowptr[i] + partial[blockIdx.x];
        rowptr[i] = r;
        cursor[i] = r;
    }
}

__global__ __launch_bounds__(256) void scatter_edges(
    const int* __restrict__ src, const int* __restrict__ dst,
    const float* __restrict__ ew, int* __restrict__ cursor,
    int2* __restrict__ csr, int E)
{
    int i = blockIdx.x * 256 + threadIdx.x;
    if (i < E) {
        int d   = dst[i];
        int pos = atomicAdd(&cursor[d], 1);
        csr[pos] = make_int2(src[i], __float_as_int(ew[i]));
    }
}

// ---------------------------------------------------------------------------
// CSR aggregation: one wave per dst row. 64 lanes x float2 = 128 cols in regs.
// No atomics. Edge records broadcast-loaded; gathers unrolled x4.
// ---------------------------------------------------------------------------
__global__ __launch_bounds__(256) void spmm_csr(
    const float* __restrict__ support, const int2* __restrict__ csr,
    const int* __restrict__ rowptr, const int* __restrict__ deg,
    float* __restrict__ agg, int N)
{
    const int lane = threadIdx.x & 63;
    const int d    = blockIdx.x * 4 + (threadIdx.x >> 6);
    if (d >= N) return;
    const int beg = rowptr[d];
    const int cnt = deg[d];
    const float2* sup2 = reinterpret_cast<const float2*>(support);

    float2 acc = make_float2(0.f, 0.f);
    int k = 0;
    for (; k + 4 <= cnt; k += 4) {
        int2 e0 = csr[beg + k + 0];
        int2 e1 = csr[beg + k + 1];
        int2 e2 = csr[beg + k + 2];
        int2 e3 = csr[beg + k + 3];
        float2 v0 = sup2[(size_t)e0.x * 64 + lane];
        float2 v1 = sup2[(size_t)e1.x * 64 + lane];
        float2 v2 = sup2[(size_t)e2.x * 64 + lane];
        float2 v3 = sup2[(size_t)e3.x * 64 + lane];
        float w0 = __int_as_float(e0.y), w1 = __int_as_float(e1.y);
        float w2 = __int_as_float(e2.y), w3 = __int_as_float(e3.y);
        acc.x = fmaf(v0.x, w0, acc.x); acc.y = fmaf(v0.y, w0, acc.y);
        acc.x = fmaf(v1.x, w1, acc.x); acc.y = fmaf(v1.y, w1, acc.y);
        acc.x = fmaf(v2.x, w2, acc.x); acc.y = fmaf(v2.y, w2, acc.y);
        acc.x = fmaf(v3.x, w3, acc.x); acc.y = fmaf(v3.y, w3, acc.y);
    }
    for (; k < cnt; ++k) {
        int2 e = csr[beg + k];
        float w = __int_as_float(e.y);
        float2 v = sup2[(size_t)e.x * 64 + lane];
        acc.x = fmaf(v.x, w, acc.x);
        acc.y = fmaf(v.y, w, acc.y);
    }
    reinterpret_cast<float2*>(agg)[(size_t)d * 64 + lane] = acc;
}

// ---------------------------------------------------------------------------
// Column stats: bnacc[0:128] = sum, bnacc[128:256] = sumsq
// ---------------------------------------------------------------------------
__global__ __launch_bounds__(256) void bn_stats(
    const float* __restrict__ agg, float* __restrict__ bnacc, int N)
{
    const int j    = threadIdx.x & 127;
    const int half = threadIdx.x >> 7;
    const int strm = blockIdx.x * 2 + half;
    const int S    = gridDim.x * 2;
    float s = 0.f, s2 = 0.f;
    for (int r = strm; r < N; r += S) {
        float v = agg[(size_t)r * 128 + j];
        s += v;
        s2 += v * v;
    }
    __shared__ float sh[512];
    sh[threadIdx.x]       = s;
    sh[256 + threadIdx.x] = s2;
    __syncthreads();
    if (threadIdx.x < 128) {
        float ts = sh[threadIdx.x] + sh[threadIdx.x + 128];
        float t2 = sh[256 + threadIdx.x] + sh[256 + threadIdx.x + 128];
        unsafeAtomicAdd(&bnacc[j], ts);
        unsafeAtomicAdd(&bnacc[128 + j], t2);
    }
}

__global__ void bn_finalize(const float* __restrict__ bnacc,
                            const float* __restrict__ gamma,
                            const float* __restrict__ beta,
                            float* __restrict__ scsh, float invN)
{
    int j = threadIdx.x;                 // 128 threads
    float mean = bnacc[j] * invN;
    float var  = bnacc[128 + j] * invN - mean * mean;
    float sc   = gamma[j] * rsqrtf(var + BN_EPS);
    scsh[j]       = sc;
    scsh[128 + j] = beta[j] - mean * sc;
}

// ---------------------------------------------------------------------------
// out = relu(agg*scale + shift) + res   (res already in d_out)
// ---------------------------------------------------------------------------
__global__ __launch_bounds__(256) void bn_apply(
    const float* __restrict__ agg, const float* __restrict__ scsh,
    float* __restrict__ out, long total4)
{
    long t = (long)blockIdx.x * 256 + threadIdx.x;
    if (t >= total4) return;
    int f4 = (int)(t & 31);
    float4 v  = reinterpret_cast<const float4*>(agg)[t];
    float4 sc = reinterpret_cast<const float4*>(scsh)[f4];
    float4 sh = reinterpret_cast<const float4*>(scsh)[32 + f4];
    float4 r  = reinterpret_cast<float4*>(out)[t];
    float4 o;
    o.x = fmaxf(fmaf(v.x, sc.x, sh.x), 0.f) + r.x;
    o.y = fmaxf(fmaf(v.y, sc.y, sh.y), 0.f) + r.y;
    o.z = fmaxf(fmaf(v.z, sc.z, sh.z), 0.f) + r.z;
    o.w = fmaxf(fmaf(v.w, sc.w, sh.w), 0.f) + r.w;
    reinterpret_cast<float4*>(out)[t] = o;
}

// ---------------------------------------------------------------------------
extern "C" void kernel_launch(void* const* d_in, const int* in_sizes, int n_in,
                              void* d_out, int out_size, void* d_ws, size_t ws_size,
                              hipStream_t stream)
{
    const float* x     = (const float*)d_in[0];
    const int*   ei    = (const int*)  d_in[1];
    const float* ew    = (const float*)d_in[2];
    const float* W     = (const float*)d_in[3];
    const float* b     = (const float*)d_in[4];
    const float* Wres  = (const float*)d_in[5];
    const float* bres  = (const float*)d_in[6];
    const float* gamma = (const float*)d_in[7];
    const float* beta  = (const float*)d_in[8];

    const int N = in_sizes[0] / DF;
    const int E = in_sizes[2];
    const int* srci = ei;          // edge_index[0]
    const int* dsti = ei + E;      // edge_index[1]

    // ws layout (4B units):
    // agg[N*128] | bnacc[256] | deg[N] | scsh[256] | support[N*128] |
    // rowptr[N] | cursor[N] | partial[256] | csr[E*2]
    float* fws     = (float*)d_ws;
    float* agg     = fws;
    float* bnacc   = agg + (size_t)N * DF;
    int*   deg     = (int*)(bnacc + 256);
    float* scsh    = (float*)(deg + N);
    float* support = scsh + 256;
    int*   rowptr  = (int*)(support + (size_t)N * DF);
    int*   cursor  = rowptr + N;
    int*   partial = cursor + N;
    int2*  csr     = (int2*)(partial + 256);
    float* out     = (float*)d_out;

    const int NB = (N + 255) / 256;   // scan blocks (<=256 required)

    // zero agg + bnacc + deg in one contiguous shot
    hipMemsetAsync(agg, 0, ((size_t)N * DF + 256 + N) * sizeof(float), stream);

    dim3 gg((N + 127) / 128, 4);
    gemm_dual<<<gg, 256, 0, stream>>>(x, W, b, Wres, bres, support, out, N);

    int eb = (E + 255) / 256;
    hist_deg<<<eb, 256, 0, stream>>>(dsti, deg, E);
    scan1<<<NB, 256, 0, stream>>>(deg, rowptr, partial, N);
    scan2<<<1, 256, 0, stream>>>(partial, NB);
    scan3<<<NB, 256, 0, stream>>>(rowptr, cursor, partial, N);
    scatter_edges<<<eb, 256, 0, stream>>>(srci, dsti, ew, cursor, csr, E);

    spmm_csr<<<(N + 3) / 4, 256, 0, stream>>>(support, csr, rowptr, deg, agg, N);

    bn_stats<<<512, 256, 0, stream>>>(agg, bnacc, N);
    bn_finalize<<<1, 128, 0, stream>>>(bnacc, gamma, beta, scsh, 1.0f / (float)N);

    long t4 = (long)N * (DF / 4);
    bn_apply<<<(int)((t4 + 255) / 256), 256, 0, stream>>>(agg, scsh, out, t4);
}

// Round 3
// 435.002 us; speedup vs baseline: 6.5573x; 1.1482x over previous
//
#include <hip/hip_runtime.h>

#define DF 128
#define BN_EPS 1e-5f

typedef short s16x8 __attribute__((ext_vector_type(8)));
typedef float f32x4 __attribute__((ext_vector_type(4)));

// fp32 -> bf16 bits, round-to-nearest-even
__device__ __forceinline__ ushort f2b(float f) {
    uint u = __float_as_uint(f);
    u += 0x7fffu + ((u >> 16) & 1u);
    return (ushort)(u >> 16);
}
__device__ __forceinline__ float b2f_lo(uint v) { return __uint_as_float(v << 16); }
__device__ __forceinline__ float b2f_hi(uint v) { return __uint_as_float(v & 0xffff0000u); }

// ---------------------------------------------------------------------------
// fp32 -> bf16 conversion, float4-vectorized
// ---------------------------------------------------------------------------
__global__ __launch_bounds__(256) void cvt_f32_bf16(
    const float* __restrict__ in, ushort* __restrict__ out, long n4)
{
    long t = (long)blockIdx.x * 256 + threadIdx.x;
    if (t >= n4) return;
    float4 v = reinterpret_cast<const float4*>(in)[t];
    ushort4 o;
    o.x = f2b(v.x); o.y = f2b(v.y); o.z = f2b(v.z); o.w = f2b(v.w);
    reinterpret_cast<ushort4*>(out)[t] = o;
}

// ---------------------------------------------------------------------------
// MFMA dual GEMM: support(bf16) = x@W^T + b ; res(fp32,d_out) = x@Wres^T + bres
// Wcat = [W ; Wres] bf16 [256][128]. One wave per 16 x-rows; x-frags held as
// B-operand (reused across 16 col-tiles); W-tile is the A-operand so each
// lane's 4 acc regs are 4 consecutive out-cols -> vector stores.
// ---------------------------------------------------------------------------
__global__ __launch_bounds__(256) void gemm_mfma(
    const ushort* __restrict__ xb, const ushort* __restrict__ Wcat,
    const float* __restrict__ b, const float* __restrict__ bres,
    ushort* __restrict__ support, float* __restrict__ res, int N)
{
    const int wave = threadIdx.x >> 6;
    const int lane = threadIdx.x & 63;
    const int r0   = (blockIdx.x * 4 + wave) * 16;
    if (r0 >= N) return;
    const int lrow = lane & 15;
    const int g4   = lane >> 4;        // 0..3
    const int koff = g4 * 8;
    const int row  = r0 + lrow;        // x row this lane owns (B col, D col)
    const bool rok = row < N;
    const int  ar  = rok ? row : (N - 1);

    s16x8 xf[4];
#pragma unroll
    for (int kb = 0; kb < 4; ++kb)
        xf[kb] = *reinterpret_cast<const s16x8*>(&xb[(size_t)ar * 128 + kb * 32 + koff]);

#pragma unroll
    for (int ct = 0; ct < 16; ++ct) {
        f32x4 acc = {0.f, 0.f, 0.f, 0.f};
#pragma unroll
        for (int kb = 0; kb < 4; ++kb) {
            s16x8 wf = *reinterpret_cast<const s16x8*>(
                &Wcat[(size_t)(ct * 16 + lrow) * 128 + kb * 32 + koff]);
            acc = __builtin_amdgcn_mfma_f32_16x16x32_bf16(wf, xf[kb], acc, 0, 0, 0);
        }
        if (rok) {
            int c0 = ct * 16 + 4 * g4;         // global out-col of acc[0]
            if (ct < 8) {
                float4 bias = *reinterpret_cast<const float4*>(&b[c0]);
                ushort4 o;
                o.x = f2b(acc[0] + bias.x); o.y = f2b(acc[1] + bias.y);
                o.z = f2b(acc[2] + bias.z); o.w = f2b(acc[3] + bias.w);
                *reinterpret_cast<ushort4*>(&support[(size_t)row * 128 + c0]) = o;
            } else {
                int c = c0 - 128;
                float4 bias = *reinterpret_cast<const float4*>(&bres[c]);
                float4 o = make_float4(acc[0] + bias.x, acc[1] + bias.y,
                                       acc[2] + bias.z, acc[3] + bias.w);
                *reinterpret_cast<float4*>(&res[(size_t)row * 128 + c]) = o;
            }
        }
    }
}

// ---------------------------------------------------------------------------
// CSR build
// ---------------------------------------------------------------------------
__global__ __launch_bounds__(256) void hist_deg(
    const int* __restrict__ dst, int* __restrict__ deg, int E)
{
    int i = blockIdx.x * 256 + threadIdx.x;
    if (i < E) atomicAdd(&deg[dst[i]], 1);
}

__global__ __launch_bounds__(256) void scan1(
    const int* __restrict__ deg, int* __restrict__ rowptr,
    int* __restrict__ partial, int N)
{
    __shared__ int sh[256];
    int i = blockIdx.x * 256 + threadIdx.x;
    int v = (i < N) ? deg[i] : 0;
    sh[threadIdx.x] = v;
    __syncthreads();
#pragma unroll
    for (int off = 1; off < 256; off <<= 1) {
        int t = (threadIdx.x >= off) ? sh[threadIdx.x - off] : 0;
        __syncthreads();
        sh[threadIdx.x] += t;
        __syncthreads();
    }
    if (i < N) rowptr[i] = sh[threadIdx.x] - v;          // exclusive
    if (threadIdx.x == 255) partial[blockIdx.x] = sh[255];
}

__global__ __launch_bounds__(256) void scan2(int* __restrict__ partial, int NB)
{
    __shared__ int sh[256];
    int v = (threadIdx.x < NB) ? partial[threadIdx.x] : 0;
    sh[threadIdx.x] = v;
    __syncthreads();
#pragma unroll
    for (int off = 1; off < 256; off <<= 1) {
        int t = (threadIdx.x >= off) ? sh[threadIdx.x - off] : 0;
        __syncthreads();
        sh[threadIdx.x] += t;
        __syncthreads();
    }
    if (threadIdx.x < NB) partial[threadIdx.x] = sh[threadIdx.x] - v;  // exclusive
}

__global__ __launch_bounds__(256) void scan3(
    int* __restrict__ rowptr, int* __restrict__ cursor,
    const int* __restrict__ partial, int N)
{
    int i = blockIdx.x * 256 + threadIdx.x;
    if (i < N) {
        int r = rowptr[i] + partial[blockIdx.x];
        rowptr[i] = r;
        cursor[i] = r;
    }
}

// packed edge record: src (16 high bits) | bf16(w) (16 low bits)
__global__ __launch_bounds__(256) void scatter_edges(
    const int* __restrict__ src, const int* __restrict__ dst,
    const float* __restrict__ ew, int* __restrict__ cursor,
    uint* __restrict__ csr, int E)
{
    int i = blockIdx.x * 256 + threadIdx.x;
    if (i < E) {
        int d   = dst[i];
        int pos = atomicAdd(&cursor[d], 1);
        csr[pos] = ((uint)src[i] << 16) | (uint)f2b(ew[i]);
    }
}

// ---------------------------------------------------------------------------
// CSR aggregation: one wave per dst row, bf16 gather (1 dword/lane/edge),
// fp32 accumulate, no atomics.
// ---------------------------------------------------------------------------
__global__ __launch_bounds__(256) void spmm_csr(
    const ushort* __restrict__ support, const uint* __restrict__ csr,
    const int* __restrict__ rowptr, const int* __restrict__ deg,
    float* __restrict__ agg, int N)
{
    const int lane = threadIdx.x & 63;
    const int d    = blockIdx.x * 4 + (threadIdx.x >> 6);
    if (d >= N) return;
    const int beg = rowptr[d];
    const int cnt = deg[d];
    const uint* sup = reinterpret_cast<const uint*>(support);

    float ax = 0.f, ay = 0.f;
    int k = 0;
    for (; k + 4 <= cnt; k += 4) {
        uint e0 = csr[beg + k + 0];
        uint e1 = csr[beg + k + 1];
        uint e2 = csr[beg + k + 2];
        uint e3 = csr[beg + k + 3];
        uint v0 = sup[(size_t)(e0 >> 16) * 64 + lane];
        uint v1 = sup[(size_t)(e1 >> 16) * 64 + lane];
        uint v2 = sup[(size_t)(e2 >> 16) * 64 + lane];
        uint v3 = sup[(size_t)(e3 >> 16) * 64 + lane];
        float w0 = b2f_lo(e0), w1 = b2f_lo(e1), w2 = b2f_lo(e2), w3 = b2f_lo(e3);
        ax = fmaf(b2f_lo(v0), w0, ax); ay = fmaf(b2f_hi(v0), w0, ay);
        ax = fmaf(b2f_lo(v1), w1, ax); ay = fmaf(b2f_hi(v1), w1, ay);
        ax = fmaf(b2f_lo(v2), w2, ax); ay = fmaf(b2f_hi(v2), w2, ay);
        ax = fmaf(b2f_lo(v3), w3, ax); ay = fmaf(b2f_hi(v3), w3, ay);
    }
    for (; k < cnt; ++k) {
        uint e = csr[beg + k];
        uint v = sup[(size_t)(e >> 16) * 64 + lane];
        float w = b2f_lo(e);
        ax = fmaf(b2f_lo(v), w, ax);
        ay = fmaf(b2f_hi(v), w, ay);
    }
    reinterpret_cast<float2*>(agg)[(size_t)d * 64 + lane] = make_float2(ax, ay);
}

// ---------------------------------------------------------------------------
// Column stats: bnacc[0:128] = sum, bnacc[128:256] = sumsq
// ---------------------------------------------------------------------------
__global__ __launch_bounds__(256) void bn_stats(
    const float* __restrict__ agg, float* __restrict__ bnacc, int N)
{
    const int j    = threadIdx.x & 127;
    const int half = threadIdx.x >> 7;
    const int strm = blockIdx.x * 2 + half;
    const int S    = gridDim.x * 2;
    float s = 0.f, s2 = 0.f;
    for (int r = strm; r < N; r += S) {
        float v = agg[(size_t)r * 128 + j];
        s += v;
        s2 += v * v;
    }
    __shared__ float sh[512];
    sh[threadIdx.x]       = s;
    sh[256 + threadIdx.x] = s2;
    __syncthreads();
    if (threadIdx.x < 128) {
        float ts = sh[threadIdx.x] + sh[threadIdx.x + 128];
        float t2 = sh[256 + threadIdx.x] + sh[256 + threadIdx.x + 128];
        unsafeAtomicAdd(&bnacc[j], ts);
        unsafeAtomicAdd(&bnacc[128 + j], t2);
    }
}

__global__ void bn_finalize(const float* __restrict__ bnacc,
                            const float* __restrict__ gamma,
                            const float* __restrict__ beta,
                            float* __restrict__ scsh, float invN)
{
    int j = threadIdx.x;                 // 128 threads
    float mean = bnacc[j] * invN;
    float var  = bnacc[128 + j] * invN - mean * mean;
    float sc   = gamma[j] * rsqrtf(var + BN_EPS);
    scsh[j]       = sc;
    scsh[128 + j] = beta[j] - mean * sc;
}

// ---------------------------------------------------------------------------
// out = relu(agg*scale + shift) + res   (res already in d_out)
// ---------------------------------------------------------------------------
__global__ __launch_bounds__(256) void bn_apply(
    const float* __restrict__ agg, const float* __restrict__ scsh,
    float* __restrict__ out, long total4)
{
    long t = (long)blockIdx.x * 256 + threadIdx.x;
    if (t >= total4) return;
    int f4 = (int)(t & 31);
    float4 v  = reinterpret_cast<const float4*>(agg)[t];
    float4 sc = reinterpret_cast<const float4*>(scsh)[f4];
    float4 sh = reinterpret_cast<const float4*>(scsh)[32 + f4];
    float4 r  = reinterpret_cast<float4*>(out)[t];
    float4 o;
    o.x = fmaxf(fmaf(v.x, sc.x, sh.x), 0.f) + r.x;
    o.y = fmaxf(fmaf(v.y, sc.y, sh.y), 0.f) + r.y;
    o.z = fmaxf(fmaf(v.z, sc.z, sh.z), 0.f) + r.z;
    o.w = fmaxf(fmaf(v.w, sc.w, sh.w), 0.f) + r.w;
    reinterpret_cast<float4*>(out)[t] = o;
}

// ---------------------------------------------------------------------------
extern "C" void kernel_launch(void* const* d_in, const int* in_sizes, int n_in,
                              void* d_out, int out_size, void* d_ws, size_t ws_size,
                              hipStream_t stream)
{
    const float* x     = (const float*)d_in[0];
    const int*   ei    = (const int*)  d_in[1];
    const float* ew    = (const float*)d_in[2];
    const float* W     = (const float*)d_in[3];
    const float* b     = (const float*)d_in[4];
    const float* Wres  = (const float*)d_in[5];
    const float* bres  = (const float*)d_in[6];
    const float* gamma = (const float*)d_in[7];
    const float* beta  = (const float*)d_in[8];

    const int N = in_sizes[0] / DF;
    const int E = in_sizes[2];
    const int* srci = ei;          // edge_index[0]
    const int* dsti = ei + E;      // edge_index[1]

    // ws layout (4B units):
    // agg[N*128] f32 | bnacc[256] f32 | deg[N] i32 | scsh[256] f32 |
    // support[N*128] bf16 | xb[N*128] bf16 | Wcat[256*128] bf16 |
    // rowptr[N] | cursor[N] | partial[256] | csr[E] u32
    float*  fws     = (float*)d_ws;
    float*  agg     = fws;
    float*  bnacc   = agg + (size_t)N * DF;
    int*    deg     = (int*)(bnacc + 256);
    float*  scsh    = (float*)(deg + N);
    ushort* supportb= (ushort*)(scsh + 256);
    ushort* xb      = supportb + (size_t)N * DF;
    ushort* Wcat    = xb + (size_t)N * DF;
    int*    rowptr  = (int*)(Wcat + 256 * DF);
    int*    cursor  = rowptr + N;
    int*    partial = cursor + N;
    uint*   csr     = (uint*)(partial + 256);
    float*  out     = (float*)d_out;

    const int NB = (N + 255) / 256;   // scan blocks (<=256 required)
    const int eb = (E + 255) / 256;

    // zero bnacc + deg (contiguous); agg is fully overwritten by spmm_csr
    hipMemsetAsync(bnacc, 0, (256 + (size_t)N) * sizeof(float), stream);

    // bf16 conversions
    long x4 = (long)N * 32;
    cvt_f32_bf16<<<(int)((x4 + 255) / 256), 256, 0, stream>>>(x, xb, x4);
    cvt_f32_bf16<<<16, 256, 0, stream>>>(W,    Wcat,            4096);
    cvt_f32_bf16<<<16, 256, 0, stream>>>(Wres, Wcat + 128 * DF, 4096);

    gemm_mfma<<<(N + 63) / 64, 256, 0, stream>>>(xb, Wcat, b, bres, supportb, out, N);

    hist_deg<<<eb, 256, 0, stream>>>(dsti, deg, E);
    scan1<<<NB, 256, 0, stream>>>(deg, rowptr, partial, N);
    scan2<<<1, 256, 0, stream>>>(partial, NB);
    scan3<<<NB, 256, 0, stream>>>(rowptr, cursor, partial, N);
    scatter_edges<<<eb, 256, 0, stream>>>(srci, dsti, ew, cursor, csr, E);

    spmm_csr<<<(N + 3) / 4, 256, 0, stream>>>(supportb, csr, rowptr, deg, agg, N);

    bn_stats<<<512, 256, 0, stream>>>(agg, bnacc, N);
    bn_finalize<<<1, 128, 0, stream>>>(bnacc, gamma, beta, scsh, 1.0f / (float)N);

    long t4 = (long)N * (DF / 4);
    bn_apply<<<(int)((t4 + 255) / 256), 256, 0, stream>>>(agg, scsh, out, t4);
}